// Round 25
// baseline (247.814 us; speedup 1.0000x reference)
//
#include <hip/hip_runtime.h>
#include <hip/hip_fp16.h>

// Swin-V2 window attention, MI355X (gfx950). Round 25.
// k_qkv v10: 3-tile async groups (72KB dbuf, 6 barriers) WITH counted-vmcnt
//   barriers (vmcnt(12): 9 loads drained, 12 stores left in flight).
//   Untested combination of two individually-proven pieces: fewer barriers
//   (R15 structure) x non-draining barriers (R21 technique).
// k_attn2 v10 + k_setup: exactly R24 (best reproducible: 240.6us).

#define NTOK 49
#define DIM 192
#define NH 6
#define BATCH 4096
#define MTOT 200704  // BATCH*NTOK

typedef __attribute__((ext_vector_type(4))) float f32x4;
typedef __attribute__((ext_vector_type(8))) _Float16 f16x8;
typedef __attribute__((ext_vector_type(4))) _Float16 f16x4h;

// ws layout (bytes)
#define W1_OFF 0                 // [18 tiles][12288] f16, XOR-swizzled
#define W2_OFF 221184            // [192][192] f16
#define BMI_OFF 294912           // [64*6][49 x 52] f16, pre-scaled by 1/ln2
#define HSC_OFF 2260992          // [6] f32, pre-scaled by 1/ln2
#define Q_OFF 4194304            // [B][6][49][32] f16 normalized*hs
#define K_OFF 81264640           // [B][6][49][32] f16 normalized
#define V_OFF 158334976          // [B][6][49][32] f16 (end ~235.4MB)

#define LOG2E 1.44269504088896f
#define SM_SHIFT 16.0f

#define MFMA16(a, b, c) __builtin_amdgcn_mfma_f32_16x16x32_f16(a, b, c, 0, 0, 0)

#define GLOAD_LDS16(gsrc, ldst)                                      \
  __builtin_amdgcn_global_load_lds(                                  \
      (const __attribute__((address_space(1))) unsigned int*)(gsrc), \
      (__attribute__((address_space(3))) unsigned int*)(ldst), 16, 0, 0)

__global__ __launch_bounds__(256) void k_setup(
    const float* __restrict__ qkv_w, const float* __restrict__ proj_w,
    const float* __restrict__ mask, const float* __restrict__ table,
    const int* __restrict__ rel_index, const float* __restrict__ ls,
    char* __restrict__ W1s, _Float16* __restrict__ W2,
    _Float16* __restrict__ bmi, float* __restrict__ hsc) {
  int idx = blockIdx.x * 256 + threadIdx.x;
  if (idx < 576 * 192) {
    int col = idx / 192, kk = idx - col * 192;
    unsigned int o = (unsigned int)(col & 31) * 384 + (unsigned int)kk * 2;
    unsigned int d = (unsigned int)(col >> 5) * 12288 +
                     (o ^ (((unsigned int)col & 7) << 4));
    *(_Float16*)(W1s + d) = (_Float16)qkv_w[idx];
  }
  if (idx < 192 * 192) W2[idx] = (_Float16)proj_w[idx];
  if (idx < NH) hsc[idx] = __expf(fminf(ls[idx], 4.60517019f)) * LOG2E;
  if (idx < 64 * NH * 2401) {
    int p = idx / 2401, rem = idx % 2401;
    int i = rem / 49, j = rem % 49;  // stored [p][i (stride 52)][j]
    int wdx = p / NH, h = p % NH;
    bmi[(size_t)p * 2548 + i * 52 + j] =
        (_Float16)((table[rel_index[i * 49 + j] * NH + h] +
                    mask[wdx * 2401 + i * 49 + j]) * LOG2E);
  }
}

// ---- QKV GEMM: 128 rows/block, 3-tile async groups, counted barriers ----
__global__ __launch_bounds__(256, 2) void k_qkv(
    const float* __restrict__ x, const char* __restrict__ W1s,
    const float* __restrict__ qkv_b, const float* __restrict__ hsc,
    _Float16* __restrict__ q16, _Float16* __restrict__ k16,
    _Float16* __restrict__ v16) {
  __shared__ __align__(16) char wlds[2][36864];  // 3 x 12KB swizzled tiles

  const int tid = threadIdx.x;
  const int lane = tid & 63;
  const int w = tid >> 6;
  const int rowbase = blockIdx.x * 128 + w * 32;
  const int L = lane & 15;
  const int g = lane >> 4;

  f16x8 ax[2][6];
#pragma unroll
  for (int rt = 0; rt < 2; ++rt) {
    const float* xr = x + (size_t)(rowbase + rt * 16 + L) * DIM + 8 * g;
#pragma unroll
    for (int kf = 0; kf < 6; ++kf) {
      f32x4 lo = *(const f32x4*)(xr + 32 * kf);
      f32x4 hi = *(const f32x4*)(xr + 32 * kf + 4);
      f16x8 v;
      v[0] = (_Float16)lo[0]; v[1] = (_Float16)lo[1];
      v[2] = (_Float16)lo[2]; v[3] = (_Float16)lo[3];
      v[4] = (_Float16)hi[0]; v[5] = (_Float16)hi[1];
      v[6] = (_Float16)hi[2]; v[7] = (_Float16)hi[3];
      ax[rt][kf] = v;
    }
  }
  int qkb[2];
#pragma unroll
  for (int rt = 0; rt < 2; ++rt) {
    int row = rowbase + rt * 16 + L;
    int bb = row / 49, n = row - bb * 49;
    qkb[rt] = bb * 9408 + n * 32;  // + h*1568 + d
  }

  // prologue: stage group 0 (tiles 0..2); full drain (only loads outstanding)
#pragma unroll
  for (int r = 0; r < 9; ++r)
    GLOAD_LDS16(W1s + (w * 9 + r) * 1024 + lane * 16,
                &wlds[0][(w * 9 + r) * 1024]);
  asm volatile("s_waitcnt vmcnt(0)" ::: "memory");
  __builtin_amdgcn_s_barrier();
  __builtin_amdgcn_sched_barrier(0);

#pragma unroll 1
  for (int grp = 0; grp < 6; ++grp) {
    const int cur = grp & 1;

    if (grp < 5) {
#pragma unroll
      for (int r = 0; r < 9; ++r)
        GLOAD_LDS16(W1s + (size_t)(grp + 1) * 36864 + (w * 9 + r) * 1024 +
                        lane * 16,
                    &wlds[cur ^ 1][(w * 9 + r) * 1024]);
      __builtin_amdgcn_sched_barrier(0);  // pin load-issue before compute
    }

    const unsigned int sw = (unsigned int)(L & 7) << 4;
#pragma unroll
    for (int tl = 0; tl < 3; ++tl) {
      const int t = grp * 3 + tl;
      const int s = t / 6;
      const int tt = t - 6 * s;
      _Float16* dst = (s == 0) ? q16 : (s == 1) ? k16 : v16;
      const char* base = &wlds[cur][tl * 12288];
      f32x4 av[2][2];  // [ct][rt], bias included
#pragma unroll
      for (int ct = 0; ct < 2; ++ct) {
        f16x8 wf[6];
#pragma unroll
        for (int kf = 0; kf < 6; ++kf) {
          unsigned int o0 = (unsigned int)(16 * ct + L) * 384 +
                            (unsigned int)kf * 64 + (unsigned int)g * 16;
          wf[kf] = *(const f16x8*)(base + (o0 ^ sw));
        }
        f32x4 a0 = {0.f, 0.f, 0.f, 0.f}, a1 = {0.f, 0.f, 0.f, 0.f};
#pragma unroll
        for (int kf = 0; kf < 6; ++kf) {
          a0 = MFMA16(wf[kf], ax[0][kf], a0);
          a1 = MFMA16(wf[kf], ax[1][kf], a1);
        }
        const f32x4 bv =
            *(const f32x4*)(qkv_b + 192 * s + 32 * tt + 16 * ct + 4 * g);
#pragma unroll
        for (int r = 0; r < 4; ++r) {
          av[ct][0][r] = a0[r] + bv[r];
          av[ct][1][r] = a1[r] + bv[r];
        }
      }
      float sc[2] = {1.f, 1.f};
      if (s < 2) {  // cosine-normalize rows of q and k
#pragma unroll
        for (int rt = 0; rt < 2; ++rt) {
          float ss = 0.f;
#pragma unroll
          for (int ct = 0; ct < 2; ++ct)
#pragma unroll
            for (int r = 0; r < 4; ++r) ss += av[ct][rt][r] * av[ct][rt][r];
          ss += __shfl_xor(ss, 16);
          ss += __shfl_xor(ss, 32);
          sc[rt] = rsqrtf(fmaxf(ss, 1e-24f));
        }
        if (s == 0) {
          const float hs = hsc[tt];
          sc[0] *= hs; sc[1] *= hs;
        }
      }
#pragma unroll
      for (int ct = 0; ct < 2; ++ct) {
        const int off = tt * 1568 + 16 * ct + 4 * g;
#pragma unroll
        for (int rt = 0; rt < 2; ++rt) {
          f16x4h pk;
#pragma unroll
          for (int r = 0; r < 4; ++r)
            pk[r] = (_Float16)(av[ct][rt][r] * sc[rt]);
          *(f16x4h*)(dst + qkb[rt] + off) = pk;
        }
      }
    }

    if (grp < 5) {
      // counted barrier: per-wave issue order is [9 loads][12 stores];
      // vmcnt retires in order, so vmcnt(12) => the 9 loads (and anything
      // older) retired while this group's 12 stores stay in flight.
      asm volatile("s_waitcnt vmcnt(12)" ::: "memory");
      __builtin_amdgcn_s_barrier();
      __builtin_amdgcn_sched_barrier(0);
    }
  }
}

// ------- attention + proj: 2 windows/block, wave = (window, head) ----------
__global__ __launch_bounds__(768, 6) void k_attn2(
    const _Float16* __restrict__ q16, const _Float16* __restrict__ k16,
    const _Float16* __restrict__ v16, const _Float16* __restrict__ bmi,
    const _Float16* __restrict__ W2, const float* __restrict__ proj_b,
    float* __restrict__ out) {
  __shared__ __align__(128) _Float16 pl[12][1024];   // 128B rows, XOR-swizzled
  __shared__ __align__(16) _Float16 ao[2][64 * 200]; // per-window O staging

  const int tid = threadIdx.x;
  const int wv = tid >> 6;         // 0..11
  const int ww = wv / 6;           // window sub-index
  const int h = wv - 6 * ww;       // head
  const int b = blockIdx.x * 2 + ww;
  const int lane = tid & 63;
  const int L = lane & 15;
  const int g = lane >> 4;

  const size_t qoff = ((size_t)b * NH + h) * 1568;  // 49*32

  // V^T B-fragments: 32 clamped scalar u16 loads (overrun j-slots hit P=0)
  f16x8 vf[2][2];
#pragma unroll
  for (int dt = 0; dt < 2; ++dt)
#pragma unroll
    for (int kf = 0; kf < 2; ++kf)
#pragma unroll
      for (int e = 0; e < 8; ++e) {
        int j = 32 * kf + 8 * g + e;
        if (j > 48) j = 48;
        vf[dt][kf][e] = v16[qoff + j * 32 + 16 * dt + L];
      }

  // K fragments (already normalized by producer)
  f16x8 kf4[4];
#pragma unroll
  for (int jt = 0; jt < 4; ++jt) {
    int jrow = 16 * jt + L; if (jrow > 48) jrow = 48;
    kf4[jt] = *(const f16x8*)(k16 + qoff + jrow * 32 + 8 * g);
  }

  char* plw = (char*)&pl[wv][0];  // 128B-aligned
  const unsigned int pswz =
      (((unsigned int)L & 1) << 6) | (((unsigned int)L & 12) << 2);
  const _Float16* bmp = bmi + ((size_t)(b & 63) * NH + h) * 2548;

#pragma unroll 1
  for (int it = 0; it < 4; ++it) {
    int irow = 16 * it + L; if (irow > 48) irow = 48;
    f16x8 qf = *(const f16x8*)(q16 + qoff + irow * 32 + 8 * g);

    f32x4 st[4];
#pragma unroll
    for (int jt = 0; jt < 4; ++jt) {
      f32x4 z = {0.f, 0.f, 0.f, 0.f};
      st[jt] = MFMA16(kf4[jt], qf, z);
    }
    // fixed-max softmax (exp2 domain): logits <= 10*log2e + eps < 16
    const _Float16* bp = bmp + (16 * it + L) * 52 + 4 * g;
    float sum = 0.f;
#pragma unroll
    for (int jt = 0; jt < 4; ++jt) {
      f16x4h bm4 = *(const f16x4h*)(bp + 16 * jt);
#pragma unroll
      for (int r = 0; r < 4; ++r) {
        int j = 16 * jt + 4 * g + r;
        float v = (j < NTOK)
                      ? exp2f(st[jt][r] + (float)bm4[r] - SM_SHIFT)
                      : 0.0f;
        st[jt][r] = v;
        sum += v;
      }
    }
    sum += __shfl_xor(sum, 16);
    sum += __shfl_xor(sum, 32);
    const float is = 1.0f / sum;

#pragma unroll
    for (int jt = 0; jt < 4; ++jt) {
      f16x4h pk;
#pragma unroll
      for (int r = 0; r < 4; ++r) pk[r] = (_Float16)(st[jt][r] * is);
      *(f16x4h*)(plw +
                 (((unsigned int)L * 128 + 32u * jt + 8u * g) ^ pswz)) = pk;
    }
    f16x8 pa0 =
        *(const f16x8*)(plw + (((unsigned int)L * 128 + 16u * g) ^ pswz));
    f16x8 pa1 = *(const f16x8*)(plw +
                                (((unsigned int)L * 128 + 64 + 16u * g) ^ pswz));
    // SWAPPED PV: D row (4g+r) = d within dt-tile, D col (L) = token row i
#pragma unroll
    for (int dt = 0; dt < 2; ++dt) {
      f32x4 o4 = {0.f, 0.f, 0.f, 0.f};
      o4 = MFMA16(vf[dt][0], pa0, o4);
      o4 = MFMA16(vf[dt][1], pa1, o4);
      f16x4h ok;
#pragma unroll
      for (int r = 0; r < 4; ++r) ok[r] = (_Float16)o4[r];
      *(f16x4h*)(&ao[ww][(16 * it + L) * 200 + 32 * h + 16 * dt + 4 * g]) = ok;
    }
  }
  __syncthreads();  // the ONLY barrier

#pragma unroll
  for (int cp = 0; cp < 2; ++cp) {
    const int ct = h + 6 * cp;
    const _Float16* wp = W2 + (size_t)(16 * ct + L) * DIM + 8 * g;
    f16x8 wfr[6];
#pragma unroll
    for (int kf = 0; kf < 6; ++kf) wfr[kf] = *(const f16x8*)(wp + 32 * kf);
    const f32x4 pbv = *(const f32x4*)(proj_b + 16 * ct + 4 * g);
#pragma unroll 1
    for (int mt = 0; mt < 4; ++mt) {
      f32x4 acc = {0.f, 0.f, 0.f, 0.f};
      // SWAPPED proj: D row (4g+r) = W2 col, D col (L) = token row
#pragma unroll
      for (int kf = 0; kf < 6; ++kf) {
        f16x8 af =
            *(const f16x8*)(&ao[ww][(16 * mt + L) * 200 + 32 * kf + 8 * g]);
        acc = MFMA16(wfr[kf], af, acc);
      }
      const int row = 16 * mt + L;
      if (row < NTOK) {
        f32x4 o;
#pragma unroll
        for (int r = 0; r < 4; ++r) o[r] = acc[r] + pbv[r];
        *(f32x4*)(&out[((size_t)b * NTOK + row) * DIM + 16 * ct + 4 * g]) = o;
      }
    }
  }
}

extern "C" void kernel_launch(void* const* d_in, const int* in_sizes, int n_in,
                              void* d_out, int out_size, void* d_ws, size_t ws_size,
                              hipStream_t stream) {
  const float* x     = (const float*)d_in[0];
  const float* mask  = (const float*)d_in[1];
  const float* qkv_w = (const float*)d_in[2];
  const float* qkv_b = (const float*)d_in[3];
  const float* ls    = (const float*)d_in[4];
  const float* tbl   = (const float*)d_in[5];
  const int*   ridx  = (const int*)d_in[6];
  const float* pw    = (const float*)d_in[7];
  const float* pb    = (const float*)d_in[8];
  float* out = (float*)d_out;
  char* ws = (char*)d_ws;

  char* W1s = ws + W1_OFF;
  _Float16* W2 = (_Float16*)(ws + W2_OFF);
  _Float16* bmi = (_Float16*)(ws + BMI_OFF);
  float* hsc = (float*)(ws + HSC_OFF);
  _Float16* q16 = (_Float16*)(ws + Q_OFF);
  _Float16* k16 = (_Float16*)(ws + K_OFF);
  _Float16* v16 = (_Float16*)(ws + V_OFF);

  hipLaunchKernelGGL(k_setup, dim3(3602), dim3(256), 0, stream,
                     qkv_w, pw, mask, tbl, ridx, ls, W1s, W2, bmi, hsc);
  hipLaunchKernelGGL(k_qkv, dim3(MTOT / 128), dim3(256), 0, stream,
                     x, W1s, qkv_b, hsc, q16, k16, v16);
  hipLaunchKernelGGL(k_attn2, dim3(BATCH / 2), dim3(768), 0, stream,
                     q16, k16, v16, bmi, W2, pb, out);
}

// Round 26
// 240.411 us; speedup vs baseline: 1.0308x; 1.0308x over previous
//
#include <hip/hip_runtime.h>
#include <hip/hip_fp16.h>

// Swin-V2 window attention, MI355X (gfx950). Round 26 = exact R24 restore
// (best reproducible configuration: 241.2 / 240.6 us across two runs).
// R25's 3-tile+counted-vmcnt combo lost (occupancy 27->18.7% outweighed
// fewer barriers); reverted.
// k_qkv v9: counted-vmcnt barriers (stores stay in flight across s_barrier),
//   2-tile async-LDS groups, (256,3), q/k cosine-normalized at the producer.
// k_attn2 v10: 2 windows/block (12 waves), fixed-max exp2 softmax,
//   swizzled 128B-row pl, operand-swapped MFMAs -> vector stores.

#define NTOK 49
#define DIM 192
#define NH 6
#define BATCH 4096
#define MTOT 200704  // BATCH*NTOK

typedef __attribute__((ext_vector_type(4))) float f32x4;
typedef __attribute__((ext_vector_type(8))) _Float16 f16x8;
typedef __attribute__((ext_vector_type(4))) _Float16 f16x4h;

// ws layout (bytes)
#define W1_OFF 0                 // [18 tiles][12288] f16, XOR-swizzled
#define W2_OFF 221184            // [192][192] f16
#define BMI_OFF 294912           // [64*6][49 x 52] f16, pre-scaled by 1/ln2
#define HSC_OFF 2260992          // [6] f32, pre-scaled by 1/ln2
#define Q_OFF 4194304            // [B][6][49][32] f16 normalized*hs
#define K_OFF 81264640           // [B][6][49][32] f16 normalized
#define V_OFF 158334976          // [B][6][49][32] f16 (end ~235.4MB)

#define LOG2E 1.44269504088896f
#define SM_SHIFT 16.0f

#define MFMA16(a, b, c) __builtin_amdgcn_mfma_f32_16x16x32_f16(a, b, c, 0, 0, 0)

#define GLOAD_LDS16(gsrc, ldst)                                      \
  __builtin_amdgcn_global_load_lds(                                  \
      (const __attribute__((address_space(1))) unsigned int*)(gsrc), \
      (__attribute__((address_space(3))) unsigned int*)(ldst), 16, 0, 0)

__global__ __launch_bounds__(256) void k_setup(
    const float* __restrict__ qkv_w, const float* __restrict__ proj_w,
    const float* __restrict__ mask, const float* __restrict__ table,
    const int* __restrict__ rel_index, const float* __restrict__ ls,
    char* __restrict__ W1s, _Float16* __restrict__ W2,
    _Float16* __restrict__ bmi, float* __restrict__ hsc) {
  int idx = blockIdx.x * 256 + threadIdx.x;
  if (idx < 576 * 192) {
    int col = idx / 192, kk = idx - col * 192;
    unsigned int o = (unsigned int)(col & 31) * 384 + (unsigned int)kk * 2;
    unsigned int d = (unsigned int)(col >> 5) * 12288 +
                     (o ^ (((unsigned int)col & 7) << 4));
    *(_Float16*)(W1s + d) = (_Float16)qkv_w[idx];
  }
  if (idx < 192 * 192) W2[idx] = (_Float16)proj_w[idx];
  if (idx < NH) hsc[idx] = __expf(fminf(ls[idx], 4.60517019f)) * LOG2E;
  if (idx < 64 * NH * 2401) {
    int p = idx / 2401, rem = idx % 2401;
    int i = rem / 49, j = rem % 49;  // stored [p][i (stride 52)][j]
    int wdx = p / NH, h = p % NH;
    bmi[(size_t)p * 2548 + i * 52 + j] =
        (_Float16)((table[rel_index[i * 49 + j] * NH + h] +
                    mask[wdx * 2401 + i * 49 + j]) * LOG2E);
  }
}

// ---- QKV GEMM: 128 rows/block, 2-tile async groups, q/k pre-normalized ----
__global__ __launch_bounds__(256, 3) void k_qkv(
    const float* __restrict__ x, const char* __restrict__ W1s,
    const float* __restrict__ qkv_b, const float* __restrict__ hsc,
    _Float16* __restrict__ q16, _Float16* __restrict__ k16,
    _Float16* __restrict__ v16) {
  __shared__ __align__(16) char wlds[2][24576];  // 2 x 12KB swizzled tiles

  const int tid = threadIdx.x;
  const int lane = tid & 63;
  const int w = tid >> 6;
  const int rowbase = blockIdx.x * 128 + w * 32;
  const int L = lane & 15;
  const int g = lane >> 4;

  f16x8 ax[2][6];
#pragma unroll
  for (int rt = 0; rt < 2; ++rt) {
    const float* xr = x + (size_t)(rowbase + rt * 16 + L) * DIM + 8 * g;
#pragma unroll
    for (int kf = 0; kf < 6; ++kf) {
      f32x4 lo = *(const f32x4*)(xr + 32 * kf);
      f32x4 hi = *(const f32x4*)(xr + 32 * kf + 4);
      f16x8 v;
      v[0] = (_Float16)lo[0]; v[1] = (_Float16)lo[1];
      v[2] = (_Float16)lo[2]; v[3] = (_Float16)lo[3];
      v[4] = (_Float16)hi[0]; v[5] = (_Float16)hi[1];
      v[6] = (_Float16)hi[2]; v[7] = (_Float16)hi[3];
      ax[rt][kf] = v;
    }
  }
  int qkb[2];
#pragma unroll
  for (int rt = 0; rt < 2; ++rt) {
    int row = rowbase + rt * 16 + L;
    int bb = row / 49, n = row - bb * 49;
    qkb[rt] = bb * 9408 + n * 32;  // + h*1568 + d
  }

  // prologue: stage group 0; full drain (only loads outstanding)
#pragma unroll
  for (int r = 0; r < 6; ++r)
    GLOAD_LDS16(W1s + (w * 6 + r) * 1024 + lane * 16,
                &wlds[0][(w * 6 + r) * 1024]);
  asm volatile("s_waitcnt vmcnt(0)" ::: "memory");
  __builtin_amdgcn_s_barrier();
  __builtin_amdgcn_sched_barrier(0);

#pragma unroll 1
  for (int grp = 0; grp < 9; ++grp) {
    const int cur = grp & 1;

    if (grp < 8) {
#pragma unroll
      for (int r = 0; r < 6; ++r)
        GLOAD_LDS16(W1s + (size_t)(grp + 1) * 24576 + (w * 6 + r) * 1024 +
                        lane * 16,
                    &wlds[cur ^ 1][(w * 6 + r) * 1024]);
      __builtin_amdgcn_sched_barrier(0);  // pin load-issue before compute
    }

    const unsigned int sw = (unsigned int)(L & 7) << 4;
#pragma unroll
    for (int tl = 0; tl < 2; ++tl) {
      const int t = grp * 2 + tl;
      const int s = t / 6;
      const int tt = t - 6 * s;
      _Float16* dst = (s == 0) ? q16 : (s == 1) ? k16 : v16;
      const char* base = &wlds[cur][tl * 12288];
      f32x4 av[2][2];  // [ct][rt], bias included
#pragma unroll
      for (int ct = 0; ct < 2; ++ct) {
        f16x8 wf[6];
#pragma unroll
        for (int kf = 0; kf < 6; ++kf) {
          unsigned int o0 = (unsigned int)(16 * ct + L) * 384 +
                            (unsigned int)kf * 64 + (unsigned int)g * 16;
          wf[kf] = *(const f16x8*)(base + (o0 ^ sw));
        }
        f32x4 a0 = {0.f, 0.f, 0.f, 0.f}, a1 = {0.f, 0.f, 0.f, 0.f};
#pragma unroll
        for (int kf = 0; kf < 6; ++kf) {
          a0 = MFMA16(wf[kf], ax[0][kf], a0);
          a1 = MFMA16(wf[kf], ax[1][kf], a1);
        }
        const f32x4 bv =
            *(const f32x4*)(qkv_b + 192 * s + 32 * tt + 16 * ct + 4 * g);
#pragma unroll
        for (int r = 0; r < 4; ++r) {
          av[ct][0][r] = a0[r] + bv[r];
          av[ct][1][r] = a1[r] + bv[r];
        }
      }
      float sc[2] = {1.f, 1.f};
      if (s < 2) {  // cosine-normalize rows of q and k
#pragma unroll
        for (int rt = 0; rt < 2; ++rt) {
          float ss = 0.f;
#pragma unroll
          for (int ct = 0; ct < 2; ++ct)
#pragma unroll
            for (int r = 0; r < 4; ++r) ss += av[ct][rt][r] * av[ct][rt][r];
          ss += __shfl_xor(ss, 16);
          ss += __shfl_xor(ss, 32);
          sc[rt] = rsqrtf(fmaxf(ss, 1e-24f));
        }
        if (s == 0) {
          const float hs = hsc[tt];
          sc[0] *= hs; sc[1] *= hs;
        }
      }
#pragma unroll
      for (int ct = 0; ct < 2; ++ct) {
        const int off = tt * 1568 + 16 * ct + 4 * g;
#pragma unroll
        for (int rt = 0; rt < 2; ++rt) {
          f16x4h pk;
#pragma unroll
          for (int r = 0; r < 4; ++r)
            pk[r] = (_Float16)(av[ct][rt][r] * sc[rt]);
          *(f16x4h*)(dst + qkb[rt] + off) = pk;
        }
      }
    }

    if (grp < 8) {
      // counted barrier: drain the 6 gload_lds (next buffer) but leave this
      // group's 8 stores in flight across the barrier.
      asm volatile("s_waitcnt vmcnt(8)" ::: "memory");
      __builtin_amdgcn_s_barrier();
      __builtin_amdgcn_sched_barrier(0);
    }
  }
}

// ------- attention + proj: 2 windows/block, wave = (window, head) ----------
__global__ __launch_bounds__(768, 6) void k_attn2(
    const _Float16* __restrict__ q16, const _Float16* __restrict__ k16,
    const _Float16* __restrict__ v16, const _Float16* __restrict__ bmi,
    const _Float16* __restrict__ W2, const float* __restrict__ proj_b,
    float* __restrict__ out) {
  __shared__ __align__(128) _Float16 pl[12][1024];   // 128B rows, XOR-swizzled
  __shared__ __align__(16) _Float16 ao[2][64 * 200]; // per-window O staging

  const int tid = threadIdx.x;
  const int wv = tid >> 6;         // 0..11
  const int ww = wv / 6;           // window sub-index
  const int h = wv - 6 * ww;       // head
  const int b = blockIdx.x * 2 + ww;
  const int lane = tid & 63;
  const int L = lane & 15;
  const int g = lane >> 4;

  const size_t qoff = ((size_t)b * NH + h) * 1568;  // 49*32

  // V^T B-fragments: 32 clamped scalar u16 loads (overrun j-slots hit P=0)
  f16x8 vf[2][2];
#pragma unroll
  for (int dt = 0; dt < 2; ++dt)
#pragma unroll
    for (int kf = 0; kf < 2; ++kf)
#pragma unroll
      for (int e = 0; e < 8; ++e) {
        int j = 32 * kf + 8 * g + e;
        if (j > 48) j = 48;
        vf[dt][kf][e] = v16[qoff + j * 32 + 16 * dt + L];
      }

  // K fragments (already normalized by producer)
  f16x8 kf4[4];
#pragma unroll
  for (int jt = 0; jt < 4; ++jt) {
    int jrow = 16 * jt + L; if (jrow > 48) jrow = 48;
    kf4[jt] = *(const f16x8*)(k16 + qoff + jrow * 32 + 8 * g);
  }

  char* plw = (char*)&pl[wv][0];  // 128B-aligned
  const unsigned int pswz =
      (((unsigned int)L & 1) << 6) | (((unsigned int)L & 12) << 2);
  const _Float16* bmp = bmi + ((size_t)(b & 63) * NH + h) * 2548;

#pragma unroll 1
  for (int it = 0; it < 4; ++it) {
    int irow = 16 * it + L; if (irow > 48) irow = 48;
    f16x8 qf = *(const f16x8*)(q16 + qoff + irow * 32 + 8 * g);

    f32x4 st[4];
#pragma unroll
    for (int jt = 0; jt < 4; ++jt) {
      f32x4 z = {0.f, 0.f, 0.f, 0.f};
      st[jt] = MFMA16(kf4[jt], qf, z);
    }
    // fixed-max softmax (exp2 domain): logits <= 10*log2e + eps < 16
    const _Float16* bp = bmp + (16 * it + L) * 52 + 4 * g;
    float sum = 0.f;
#pragma unroll
    for (int jt = 0; jt < 4; ++jt) {
      f16x4h bm4 = *(const f16x4h*)(bp + 16 * jt);
#pragma unroll
      for (int r = 0; r < 4; ++r) {
        int j = 16 * jt + 4 * g + r;
        float v = (j < NTOK)
                      ? exp2f(st[jt][r] + (float)bm4[r] - SM_SHIFT)
                      : 0.0f;
        st[jt][r] = v;
        sum += v;
      }
    }
    sum += __shfl_xor(sum, 16);
    sum += __shfl_xor(sum, 32);
    const float is = 1.0f / sum;

#pragma unroll
    for (int jt = 0; jt < 4; ++jt) {
      f16x4h pk;
#pragma unroll
      for (int r = 0; r < 4; ++r) pk[r] = (_Float16)(st[jt][r] * is);
      *(f16x4h*)(plw +
                 (((unsigned int)L * 128 + 32u * jt + 8u * g) ^ pswz)) = pk;
    }
    f16x8 pa0 =
        *(const f16x8*)(plw + (((unsigned int)L * 128 + 16u * g) ^ pswz));
    f16x8 pa1 = *(const f16x8*)(plw +
                                (((unsigned int)L * 128 + 64 + 16u * g) ^ pswz));
    // SWAPPED PV: D row (4g+r) = d within dt-tile, D col (L) = token row i
#pragma unroll
    for (int dt = 0; dt < 2; ++dt) {
      f32x4 o4 = {0.f, 0.f, 0.f, 0.f};
      o4 = MFMA16(vf[dt][0], pa0, o4);
      o4 = MFMA16(vf[dt][1], pa1, o4);
      f16x4h ok;
#pragma unroll
      for (int r = 0; r < 4; ++r) ok[r] = (_Float16)o4[r];
      *(f16x4h*)(&ao[ww][(16 * it + L) * 200 + 32 * h + 16 * dt + 4 * g]) = ok;
    }
  }
  __syncthreads();  // the ONLY barrier

#pragma unroll
  for (int cp = 0; cp < 2; ++cp) {
    const int ct = h + 6 * cp;
    const _Float16* wp = W2 + (size_t)(16 * ct + L) * DIM + 8 * g;
    f16x8 wfr[6];
#pragma unroll
    for (int kf = 0; kf < 6; ++kf) wfr[kf] = *(const f16x8*)(wp + 32 * kf);
    const f32x4 pbv = *(const f32x4*)(proj_b + 16 * ct + 4 * g);
#pragma unroll 1
    for (int mt = 0; mt < 4; ++mt) {
      f32x4 acc = {0.f, 0.f, 0.f, 0.f};
      // SWAPPED proj: D row (4g+r) = W2 col, D col (L) = token row
#pragma unroll
      for (int kf = 0; kf < 6; ++kf) {
        f16x8 af =
            *(const f16x8*)(&ao[ww][(16 * mt + L) * 200 + 32 * kf + 8 * g]);
        acc = MFMA16(wfr[kf], af, acc);
      }
      const int row = 16 * mt + L;
      if (row < NTOK) {
        f32x4 o;
#pragma unroll
        for (int r = 0; r < 4; ++r) o[r] = acc[r] + pbv[r];
        *(f32x4*)(&out[((size_t)b * NTOK + row) * DIM + 16 * ct + 4 * g]) = o;
      }
    }
  }
}

extern "C" void kernel_launch(void* const* d_in, const int* in_sizes, int n_in,
                              void* d_out, int out_size, void* d_ws, size_t ws_size,
                              hipStream_t stream) {
  const float* x     = (const float*)d_in[0];
  const float* mask  = (const float*)d_in[1];
  const float* qkv_w = (const float*)d_in[2];
  const float* qkv_b = (const float*)d_in[3];
  const float* ls    = (const float*)d_in[4];
  const float* tbl   = (const float*)d_in[5];
  const int*   ridx  = (const int*)d_in[6];
  const float* pw    = (const float*)d_in[7];
  const float* pb    = (const float*)d_in[8];
  float* out = (float*)d_out;
  char* ws = (char*)d_ws;

  char* W1s = ws + W1_OFF;
  _Float16* W2 = (_Float16*)(ws + W2_OFF);
  _Float16* bmi = (_Float16*)(ws + BMI_OFF);
  float* hsc = (float*)(ws + HSC_OFF);
  _Float16* q16 = (_Float16*)(ws + Q_OFF);
  _Float16* k16 = (_Float16*)(ws + K_OFF);
  _Float16* v16 = (_Float16*)(ws + V_OFF);

  hipLaunchKernelGGL(k_setup, dim3(3602), dim3(256), 0, stream,
                     qkv_w, pw, mask, tbl, ridx, ls, W1s, W2, bmi, hsc);
  hipLaunchKernelGGL(k_qkv, dim3(MTOT / 128), dim3(256), 0, stream,
                     x, W1s, qkv_b, hsc, q16, k16, v16);
  hipLaunchKernelGGL(k_attn2, dim3(BATCH / 2), dim3(768), 0, stream,
                     q16, k16, v16, bmi, W2, pb, out);
}